// Round 1
// baseline (1744.934 us; speedup 1.0000x reference)
//
#include <hip/hip_runtime.h>
#include <hip/hip_bf16.h>

#define L_NUM 20
#define CC 128
#define TB 8192
#define BB 8
#define TT 64

#define NCONV (L_NUM * 3 * 256 * 128)
#define NMAT  (L_NUM * 128 * 128)

typedef __attribute__((ext_vector_type(4))) float f32x4;
typedef __attribute__((ext_vector_type(8))) short bf16x8;

static const int DILS[L_NUM] = {1, 2, 4, 8, 16, 32, 64, 128, 256, 512,
                                1, 2, 4, 8, 16, 32, 64, 128, 256, 512};

__device__ __forceinline__ unsigned short f2b(float f) {
  union { __hip_bfloat16 h; unsigned short u; } cv;
  cv.h = __float2bfloat16(f);
  return cv.u;
}

// byte offset into a [64 t][128 c] bf16 LDS tile, XOR-swizzled (G4: row-major
// 256B-stride rows are a 16-way bank conflict on ds_read_b128 without this)
__device__ __forceinline__ int swz(int t, int cbyte) {
  return (t * 256 + cbyte) ^ ((t & 7) << 4);
}

__global__ void prep_kernel(const float* __restrict__ Wconv,
                            const float* __restrict__ Wout,
                            const float* __restrict__ Wskip,
                            unsigned short* __restrict__ wc,
                            unsigned short* __restrict__ wo,
                            unsigned short* __restrict__ wsk) {
  int i = blockIdx.x * 256 + threadIdx.x;
  if (i < NCONV) {
    // dst [l][k][o][c] <- src [l][o][c][k]
    int c = i & 127;
    int o = (i >> 7) & 255;
    int lk = i >> 15;
    int k = lk % 3;
    int l = lk / 3;
    wc[i] = f2b(Wconv[((size_t)(l * 256 + o) * 128 + c) * 3 + k]);
  }
  if (i < NMAT) {
    wo[i]  = f2b(Wout[i]);
    wsk[i] = f2b(Wskip[i]);
  }
}

__global__ __launch_bounds__(256, 2) void layer_kernel(
    const float* __restrict__ xin,        // [B][C][T] f32
    float* __restrict__ xout,             // [B][C][T] f32
    const unsigned short* __restrict__ Wc,  // [3][256][128] bf16
    const float* __restrict__ bconv,        // [256]
    const unsigned short* __restrict__ Wo,  // [128][128] bf16
    const float* __restrict__ bout,         // [128]
    const unsigned short* __restrict__ Wsk, // [128][128] bf16
    const float* __restrict__ bskip,        // [128]
    float* __restrict__ skipo,              // [B][S][T] f32 (this layer's slice)
    int dil, int last) {
  __shared__ unsigned short Xs[3][TT * CC];  // 3 tap tiles, 16 KB each
  unsigned short* Zs = &Xs[0][0];            // z tile overlays tap0 (barriered)

  const int tid = threadIdx.x;
  const int lane = tid & 63;
  const int w = tid >> 6;          // wave 0..3
  const int lo = lane & 15;
  const int hi = lane >> 4;
  const int b = blockIdx.y;
  const int t0 = blockIdx.x * TT;

  const float* xb = xin + (size_t)b * CC * TB;

  // ---- stage 3 tap tiles: global f32 (coalesced along t) -> bf16 LDS [t][c]
  for (int k = 0; k < 3; ++k) {
    int tg = t0 + (k - 2) * dil + lane;    // this lane's global t for tap k
    int tgc = tg < 0 ? 0 : tg;
    bool ok = tg >= 0;
#pragma unroll
    for (int it = 0; it < 8; ++it) {
      int c0 = it * 16 + w * 4;
      unsigned int u[4];
#pragma unroll
      for (int i2 = 0; i2 < 4; ++i2) {
        float v = xb[(size_t)(c0 + i2) * TB + tgc];
        u[i2] = f2b(ok ? v : 0.f);
      }
      uint2 p;
      p.x = u[0] | (u[1] << 16);
      p.y = u[2] | (u[3] << 16);
      *reinterpret_cast<uint2*>(reinterpret_cast<char*>(&Xs[k][0]) +
                                swz(lane, c0 * 2)) = p;
    }
  }
  __syncthreads();

  // ---- conv GEMM: y[256][64] = sum_k Wk(256x128) @ Xk(128x64)
  // wave w owns a-rows [32w,32w+32) and g-rows [128+32w, 128+32w+32)
  f32x4 zero4 = {0.f, 0.f, 0.f, 0.f};
  f32x4 accA[2][4], accG[2][4];
#pragma unroll
  for (int r = 0; r < 2; ++r)
#pragma unroll
    for (int j = 0; j < 4; ++j) { accA[r][j] = zero4; accG[r][j] = zero4; }

#pragma unroll
  for (int k = 0; k < 3; ++k) {
    const unsigned short* Wk = Wc + k * 256 * 128;
#pragma unroll
    for (int kk = 0; kk < 4; ++kk) {
      int c0 = kk * 32 + hi * 8;
      bf16x8 aA0 = *reinterpret_cast<const bf16x8*>(Wk + (w * 32 + lo) * 128 + c0);
      bf16x8 aA1 = *reinterpret_cast<const bf16x8*>(Wk + (w * 32 + 16 + lo) * 128 + c0);
      bf16x8 aG0 = *reinterpret_cast<const bf16x8*>(Wk + (128 + w * 32 + lo) * 128 + c0);
      bf16x8 aG1 = *reinterpret_cast<const bf16x8*>(Wk + (128 + w * 32 + 16 + lo) * 128 + c0);
#pragma unroll
      for (int j = 0; j < 4; ++j) {
        bf16x8 bx = *reinterpret_cast<const bf16x8*>(
            reinterpret_cast<const char*>(&Xs[k][0]) + swz(j * 16 + lo, c0 * 2));
        accA[0][j] = __builtin_amdgcn_mfma_f32_16x16x32_bf16(aA0, bx, accA[0][j], 0, 0, 0);
        accA[1][j] = __builtin_amdgcn_mfma_f32_16x16x32_bf16(aA1, bx, accA[1][j], 0, 0, 0);
        accG[0][j] = __builtin_amdgcn_mfma_f32_16x16x32_bf16(aG0, bx, accG[0][j], 0, 0, 0);
        accG[1][j] = __builtin_amdgcn_mfma_f32_16x16x32_bf16(aG1, bx, accG[1][j], 0, 0, 0);
      }
    }
  }

  // ---- gated activation: z = tanh(a+ba) * sigmoid(g+bg), keep f32 in regs,
  // write bf16 z tile [t][c] into LDS (overlaying tap0: barrier first)
  float bcA[2][4], bcG[2][4];
#pragma unroll
  for (int r = 0; r < 2; ++r)
#pragma unroll
    for (int reg = 0; reg < 4; ++reg) {
      int row = w * 32 + r * 16 + hi * 4 + reg;
      bcA[r][reg] = bconv[row];
      bcG[r][reg] = bconv[128 + row];
    }

  __syncthreads();  // all waves done reading Xs before z overwrites tap0

  f32x4 zreg[2][4];
#pragma unroll
  for (int r = 0; r < 2; ++r) {
#pragma unroll
    for (int j = 0; j < 4; ++j) {
      f32x4 zv;
#pragma unroll
      for (int reg = 0; reg < 4; ++reg) {
        float a = accA[r][j][reg] + bcA[r][reg];
        float g = accG[r][j][reg] + bcG[r][reg];
        float ea = __expf(2.f * a);
        float th = (ea - 1.f) / (ea + 1.f);
        float sg = 1.f / (1.f + __expf(-g));
        zv[reg] = th * sg;
      }
      zreg[r][j] = zv;
      unsigned int u0 = f2b(zv[0]), u1 = f2b(zv[1]), u2 = f2b(zv[2]), u3 = f2b(zv[3]);
      uint2 p;
      p.x = u0 | (u1 << 16);
      p.y = u2 | (u3 << 16);
      int t = j * 16 + lo;
      int cB = w * 32 + r * 16 + hi * 4;  // reg 0..3 = consecutive c
      *reinterpret_cast<uint2*>(reinterpret_cast<char*>(Zs) + swz(t, cB * 2)) = p;
    }
  }
  __syncthreads();

  // ---- skip/out GEMMs: [128x128] @ z[128x64]
  f32x4 accS[2][4], accO[2][4];
#pragma unroll
  for (int r = 0; r < 2; ++r)
#pragma unroll
    for (int j = 0; j < 4; ++j) { accS[r][j] = zero4; accO[r][j] = zero4; }

#pragma unroll
  for (int kk = 0; kk < 4; ++kk) {
    int c0 = kk * 32 + hi * 8;
    bf16x8 aS0 = *reinterpret_cast<const bf16x8*>(Wsk + (w * 32 + lo) * 128 + c0);
    bf16x8 aS1 = *reinterpret_cast<const bf16x8*>(Wsk + (w * 32 + 16 + lo) * 128 + c0);
    bf16x8 aO0 = *reinterpret_cast<const bf16x8*>(Wo + (w * 32 + lo) * 128 + c0);
    bf16x8 aO1 = *reinterpret_cast<const bf16x8*>(Wo + (w * 32 + 16 + lo) * 128 + c0);
#pragma unroll
    for (int j = 0; j < 4; ++j) {
      bf16x8 bx = *reinterpret_cast<const bf16x8*>(
          reinterpret_cast<const char*>(Zs) + swz(j * 16 + lo, c0 * 2));
      accS[0][j] = __builtin_amdgcn_mfma_f32_16x16x32_bf16(aS0, bx, accS[0][j], 0, 0, 0);
      accS[1][j] = __builtin_amdgcn_mfma_f32_16x16x32_bf16(aS1, bx, accS[1][j], 0, 0, 0);
      accO[0][j] = __builtin_amdgcn_mfma_f32_16x16x32_bf16(aO0, bx, accO[0][j], 0, 0, 0);
      accO[1][j] = __builtin_amdgcn_mfma_f32_16x16x32_bf16(aO1, bx, accO[1][j], 0, 0, 0);
    }
  }

  // ---- epilogue: skip store, residual add, x store
  float bsk[2][4], bo[2][4];
#pragma unroll
  for (int r = 0; r < 2; ++r)
#pragma unroll
    for (int reg = 0; reg < 4; ++reg) {
      int row = w * 32 + r * 16 + hi * 4 + reg;
      bsk[r][reg] = bskip[row];
      bo[r][reg] = bout[row];
    }

  float* xob = xout + (size_t)b * CC * TB;
  float* skb = skipo + (size_t)b * 128 * TB;
#pragma unroll
  for (int r = 0; r < 2; ++r) {
#pragma unroll
    for (int j = 0; j < 4; ++j) {
      int t = t0 + j * 16 + lo;
#pragma unroll
      for (int reg = 0; reg < 4; ++reg) {
        int row = w * 32 + r * 16 + hi * 4 + reg;
        skb[(size_t)row * TB + t] = accS[r][j][reg] + bsk[r][reg];
        float nv = last ? zreg[r][j][reg] : (accO[r][j][reg] + bo[r][reg]);
        xob[(size_t)row * TB + t] = nv + xb[(size_t)row * TB + t];
      }
    }
  }
}

extern "C" void kernel_launch(void* const* d_in, const int* in_sizes, int n_in,
                              void* d_out, int out_size, void* d_ws, size_t ws_size,
                              hipStream_t stream) {
  const float* x0    = (const float*)d_in[0];
  const float* Wconv = (const float*)d_in[1];
  const float* bconv = (const float*)d_in[2];
  const float* Wout  = (const float*)d_in[3];
  const float* bout  = (const float*)d_in[4];
  const float* Wskip = (const float*)d_in[5];
  const float* bskip = (const float*)d_in[6];

  unsigned short* wc  = (unsigned short*)d_ws;   // [L][3][256][128] bf16
  unsigned short* wo  = wc + NCONV;              // [L][128][128] bf16
  unsigned short* wsk = wo + NMAT;               // [L][128][128] bf16
  float* bufA = (float*)(wsk + NMAT);            // [B][C][T] f32 scratch x

  float* outx  = (float*)d_out;                  // final x region (buf B)
  float* skips = outx + (size_t)BB * CC * TB;    // [L][B][S][T]

  prep_kernel<<<(NCONV + 255) / 256, 256, 0, stream>>>(Wconv, Wout, Wskip, wc, wo, wsk);

  for (int l = 0; l < L_NUM; ++l) {
    // buffer parity: layer0 d_in->A; odd A->d_out; even d_out->A. layer19 -> d_out.
    const float* xi = (l == 0) ? x0 : ((l & 1) ? bufA : outx);
    float* xo = (l == 0) ? bufA : ((l & 1) ? outx : bufA);
    layer_kernel<<<dim3(TB / TT, BB), 256, 0, stream>>>(
        xi, xo,
        wc + (size_t)l * 3 * 256 * 128, bconv + (size_t)l * 256,
        wo + (size_t)l * 128 * 128, bout + (size_t)l * 128,
        wsk + (size_t)l * 128 * 128, bskip + (size_t)l * 128,
        skips + (size_t)l * BB * 128 * TB,
        DILS[l], l == L_NUM - 1 ? 1 : 0);
  }
}

// Round 2
// 1049.790 us; speedup vs baseline: 1.6622x; 1.6622x over previous
//
#include <hip/hip_runtime.h>
#include <hip/hip_bf16.h>

#define L_NUM 20
#define CC 128
#define TB 8192
#define BB 8
#define TT 64

#define NCONV (L_NUM * 3 * 256 * 128)
#define NMAT  (L_NUM * 128 * 128)
#define XN    ((size_t)BB * TB * CC)   // elements per bf16 x plane

typedef __attribute__((ext_vector_type(4))) float f32x4;
typedef __attribute__((ext_vector_type(8))) short bf16x8;
typedef unsigned int u32;

static const int DILS[L_NUM] = {1, 2, 4, 8, 16, 32, 64, 128, 256, 512,
                                1, 2, 4, 8, 16, 32, 64, 128, 256, 512};

__device__ __forceinline__ unsigned short f2b(float f) {
  union { __hip_bfloat16 h; unsigned short u; } cv;
  cv.h = __float2bfloat16(f);
  return cv.u;
}
__device__ __forceinline__ float b2fu(u32 u) {
  union { u32 u; float f; } cv;
  cv.u = u << 16;
  return cv.f;
}

// byte offset into a [64 t][128 c] bf16 LDS tile, XOR-swizzled (G4)
__device__ __forceinline__ int swz(int t, int cbyte) {
  return (t * 256 + cbyte) ^ ((t & 7) << 4);
}

// async global->LDS, 16B per lane; LDS dest = wave-uniform base + lane*16
__device__ __forceinline__ void gload16(const void* g, void* l) {
  __builtin_amdgcn_global_load_lds(
      (const __attribute__((address_space(1))) u32*)g,
      (__attribute__((address_space(3))) u32*)l, 16, 0, 0);
}

__global__ void prep_kernel(const float* __restrict__ Wconv,
                            const float* __restrict__ Wout,
                            const float* __restrict__ Wskip,
                            unsigned short* __restrict__ wc,
                            unsigned short* __restrict__ wo,
                            unsigned short* __restrict__ wsk,
                            unsigned short* __restrict__ zp) {
  int i = blockIdx.x * 256 + threadIdx.x;
  if (i < 128) zp[i] = 0;
  if (i < NCONV) {
    // dst [l][k][o][c] <- src [l][o][c][k]
    int c = i & 127;
    int o = (i >> 7) & 255;
    int lk = i >> 15;
    int k = lk % 3;
    int l = lk / 3;
    wc[i] = f2b(Wconv[((size_t)(l * 256 + o) * 128 + c) * 3 + k]);
  }
  if (i < NMAT) {
    wo[i]  = f2b(Wout[i]);
    wsk[i] = f2b(Wskip[i]);
  }
}

// x0 f32 [B][C][T] -> hi/lo bf16 [B][T][C] (swizzle-free global layout)
__global__ __launch_bounds__(256) void x0t_kernel(const float* __restrict__ x0,
                                                  unsigned short* __restrict__ hi,
                                                  unsigned short* __restrict__ lo) {
  __shared__ unsigned short Hs[TT * CC], Ls[TT * CC];
  const int tid = threadIdx.x, lane = tid & 63, w = tid >> 6;
  const int b = blockIdx.y, t0 = blockIdx.x * TT;
  const float* xb = x0 + (size_t)b * CC * TB;
#pragma unroll
  for (int it = 0; it < 8; ++it) {
    int c0 = it * 16 + w * 4;
    u32 hu[4], lu[4];
#pragma unroll
    for (int i2 = 0; i2 < 4; ++i2) {
      float v = xb[(size_t)(c0 + i2) * TB + t0 + lane];
      unsigned short h = f2b(v);
      hu[i2] = h;
      lu[i2] = f2b(v - b2fu(h));
    }
    uint2 hp, lp;
    hp.x = hu[0] | (hu[1] << 16); hp.y = hu[2] | (hu[3] << 16);
    lp.x = lu[0] | (lu[1] << 16); lp.y = lu[2] | (lu[3] << 16);
    *reinterpret_cast<uint2*>(reinterpret_cast<char*>(Hs) + swz(lane, c0 * 2)) = hp;
    *reinterpret_cast<uint2*>(reinterpret_cast<char*>(Ls) + swz(lane, c0 * 2)) = lp;
  }
  __syncthreads();
  unsigned short* hb = hi + ((size_t)b * TB + t0) * CC;
  unsigned short* lb = lo + ((size_t)b * TB + t0) * CC;
#pragma unroll
  for (int it = 0; it < 4; ++it) {
    int o = it * 4096 + tid * 16;
    int t = o >> 8;
    int cb = (o & 255) ^ ((t & 7) << 4);
    *reinterpret_cast<f32x4*>(reinterpret_cast<char*>(hb) + (size_t)t * 256 + cb) =
        *reinterpret_cast<f32x4*>(reinterpret_cast<char*>(Hs) + o);
    *reinterpret_cast<f32x4*>(reinterpret_cast<char*>(lb) + (size_t)t * 256 + cb) =
        *reinterpret_cast<f32x4*>(reinterpret_cast<char*>(Ls) + o);
  }
}

__global__ __launch_bounds__(256, 2) void layer_kernel(
    const unsigned short* __restrict__ hin,   // [B][T][C] bf16 (hi plane)
    unsigned short* __restrict__ hout,        // same (unused if last)
    unsigned short* __restrict__ lob,         // lo plane [B][T][C]
    const unsigned short* __restrict__ zpage, // 256B zeros
    const unsigned short* __restrict__ Wc,    // [3][256][128] bf16
    const float* __restrict__ bconv,          // [256]
    const unsigned short* __restrict__ Wo,    // [128][128] bf16
    const float* __restrict__ bout,           // [128]
    const unsigned short* __restrict__ Wsk,   // [128][128] bf16
    const float* __restrict__ bskip,          // [128]
    float* __restrict__ skipo,                // [B][S][T] f32 slice
    float* __restrict__ fxout,                // [B][C][T] f32 (last only)
    int dil, int last) {
  __shared__ unsigned short Xs[3][TT * CC];  // 3 tap tiles, 16 KB each

  const int tid = threadIdx.x;
  const int lane = tid & 63;
  const int w = tid >> 6;
  const int lo16 = lane & 15;
  const int hi4 = lane >> 4;
  const int b = blockIdx.y;
  const int t0 = blockIdx.x * TT;

  const unsigned short* hb = hin + (size_t)b * TB * CC;

  // ---- stage 3 taps via global_load_lds (linear LDS, pre-swizzled source)
#pragma unroll
  for (int k = 0; k < 3; ++k) {
    int tbase = t0 + (k - 2) * dil;
#pragma unroll
    for (int i = 0; i < 4; ++i) {
      int o = w * 4096 + i * 1024 + lane * 16;
      int tl = o >> 8;
      int cb = (o & 255) ^ ((tl & 7) << 4);
      int tg = tbase + tl;
      const char* src = (tg >= 0)
          ? (reinterpret_cast<const char*>(hb + (size_t)tg * CC) + cb)
          : (reinterpret_cast<const char*>(zpage) + cb);
      gload16(src, reinterpret_cast<char*>(&Xs[k][0]) + w * 4096 + i * 1024);
    }
  }
  __syncthreads();

  // ---- conv GEMM: y[256][64] = sum_k Wk(256x128) @ Xk(128x64)
  f32x4 zero4 = {0.f, 0.f, 0.f, 0.f};
  f32x4 accA[2][4], accG[2][4];
#pragma unroll
  for (int r = 0; r < 2; ++r)
#pragma unroll
    for (int j = 0; j < 4; ++j) { accA[r][j] = zero4; accG[r][j] = zero4; }

#pragma unroll
  for (int k = 0; k < 3; ++k) {
    const unsigned short* Wk = Wc + k * 256 * 128;
#pragma unroll
    for (int kk = 0; kk < 4; ++kk) {
      int c0 = kk * 32 + hi4 * 8;
      bf16x8 aA0 = *reinterpret_cast<const bf16x8*>(Wk + (w * 32 + lo16) * 128 + c0);
      bf16x8 aA1 = *reinterpret_cast<const bf16x8*>(Wk + (w * 32 + 16 + lo16) * 128 + c0);
      bf16x8 aG0 = *reinterpret_cast<const bf16x8*>(Wk + (128 + w * 32 + lo16) * 128 + c0);
      bf16x8 aG1 = *reinterpret_cast<const bf16x8*>(Wk + (128 + w * 32 + 16 + lo16) * 128 + c0);
#pragma unroll
      for (int j = 0; j < 4; ++j) {
        bf16x8 bx = *reinterpret_cast<const bf16x8*>(
            reinterpret_cast<const char*>(&Xs[k][0]) + swz(j * 16 + lo16, c0 * 2));
        accA[0][j] = __builtin_amdgcn_mfma_f32_16x16x32_bf16(aA0, bx, accA[0][j], 0, 0, 0);
        accA[1][j] = __builtin_amdgcn_mfma_f32_16x16x32_bf16(aA1, bx, accA[1][j], 0, 0, 0);
        accG[0][j] = __builtin_amdgcn_mfma_f32_16x16x32_bf16(aG0, bx, accG[0][j], 0, 0, 0);
        accG[1][j] = __builtin_amdgcn_mfma_f32_16x16x32_bf16(aG1, bx, accG[1][j], 0, 0, 0);
      }
    }
  }

  // ---- gated activation -> z bf16 tile into Xs[0] (after all taps read)
  float bcA[2][4], bcG[2][4];
#pragma unroll
  for (int r = 0; r < 2; ++r)
#pragma unroll
    for (int reg = 0; reg < 4; ++reg) {
      int row = w * 32 + r * 16 + hi4 * 4 + reg;
      bcA[r][reg] = bconv[row];
      bcG[r][reg] = bconv[128 + row];
    }

  __syncthreads();

#pragma unroll
  for (int r = 0; r < 2; ++r) {
#pragma unroll
    for (int j = 0; j < 4; ++j) {
      u32 zu[4];
#pragma unroll
      for (int reg = 0; reg < 4; ++reg) {
        float a = accA[r][j][reg] + bcA[r][reg];
        float g = accG[r][j][reg] + bcG[r][reg];
        float ea = __expf(2.f * a);
        float th = (ea - 1.f) / (ea + 1.f);
        float sg = 1.f / (1.f + __expf(-g));
        zu[reg] = f2b(th * sg);
      }
      uint2 p;
      p.x = zu[0] | (zu[1] << 16);
      p.y = zu[2] | (zu[3] << 16);
      int t = j * 16 + lo16;
      int cB = w * 32 + r * 16 + hi4 * 4;
      *reinterpret_cast<uint2*>(reinterpret_cast<char*>(&Xs[0][0]) + swz(t, cB * 2)) = p;
    }
  }
  __syncthreads();

  // ---- skip/out GEMMs: [128x128] @ z[128x64]
  f32x4 accS[2][4], accO[2][4];
#pragma unroll
  for (int r = 0; r < 2; ++r)
#pragma unroll
    for (int j = 0; j < 4; ++j) { accS[r][j] = zero4; accO[r][j] = zero4; }

#pragma unroll
  for (int kk = 0; kk < 4; ++kk) {
    int c0 = kk * 32 + hi4 * 8;
    bf16x8 aS0 = *reinterpret_cast<const bf16x8*>(Wsk + (w * 32 + lo16) * 128 + c0);
    bf16x8 aS1 = *reinterpret_cast<const bf16x8*>(Wsk + (w * 32 + 16 + lo16) * 128 + c0);
    bf16x8 aO0 = *reinterpret_cast<const bf16x8*>(Wo + (w * 32 + lo16) * 128 + c0);
    bf16x8 aO1 = *reinterpret_cast<const bf16x8*>(Wo + (w * 32 + 16 + lo16) * 128 + c0);
#pragma unroll
    for (int j = 0; j < 4; ++j) {
      bf16x8 bx = *reinterpret_cast<const bf16x8*>(
          reinterpret_cast<const char*>(&Xs[0][0]) + swz(j * 16 + lo16, c0 * 2));
      accS[0][j] = __builtin_amdgcn_mfma_f32_16x16x32_bf16(aS0, bx, accS[0][j], 0, 0, 0);
      accS[1][j] = __builtin_amdgcn_mfma_f32_16x16x32_bf16(aS1, bx, accS[1][j], 0, 0, 0);
      accO[0][j] = __builtin_amdgcn_mfma_f32_16x16x32_bf16(aO0, bx, accO[0][j], 0, 0, 0);
      accO[1][j] = __builtin_amdgcn_mfma_f32_16x16x32_bf16(aO1, bx, accO[1][j], 0, 0, 0);
    }
  }

  // ---- epilogue
  float bsk[2][4], bo[2][4];
#pragma unroll
  for (int r = 0; r < 2; ++r)
#pragma unroll
    for (int reg = 0; reg < 4; ++reg) {
      int row = w * 32 + r * 16 + hi4 * 4 + reg;
      bsk[r][reg] = bskip[row];
      bo[r][reg] = bout[row];
    }

  __syncthreads();  // GEMM2 done: Xs[0]/Xs[1] reusable; Xs[2] still holds tap2 (hi_in)

  float* skb = skipo + (size_t)b * CC * TB;
  float* fxb = fxout + (size_t)b * CC * TB;
  const unsigned short* lrow = lob + ((size_t)b * TB + t0) * CC;

#pragma unroll
  for (int r = 0; r < 2; ++r) {
#pragma unroll
    for (int j = 0; j < 4; ++j) {
      int t = j * 16 + lo16;
      int cB = w * 32 + r * 16 + hi4 * 4;
      uint2 hp = *reinterpret_cast<const uint2*>(
          reinterpret_cast<const char*>(&Xs[2][0]) + swz(t, cB * 2));
      uint2 lp = *reinterpret_cast<const uint2*>(
          reinterpret_cast<const char*>(lrow) + (size_t)t * 256 + cB * 2);
      u32 hu[4] = {hp.x & 0xffffu, hp.x >> 16, hp.y & 0xffffu, hp.y >> 16};
      u32 lu[4] = {lp.x & 0xffffu, lp.x >> 16, lp.y & 0xffffu, lp.y >> 16};
      float vout[4];
      if (last) {
        uint2 zp = *reinterpret_cast<const uint2*>(
            reinterpret_cast<const char*>(&Xs[0][0]) + swz(t, cB * 2));
        u32 zu[4] = {zp.x & 0xffffu, zp.x >> 16, zp.y & 0xffffu, zp.y >> 16};
#pragma unroll
        for (int reg = 0; reg < 4; ++reg)
          vout[reg] = b2fu(zu[reg]) + b2fu(hu[reg]) + b2fu(lu[reg]);
      } else {
#pragma unroll
        for (int reg = 0; reg < 4; ++reg)
          vout[reg] = accO[r][j][reg] + bo[r][reg] + b2fu(hu[reg]) + b2fu(lu[reg]);
      }
#pragma unroll
      for (int reg = 0; reg < 4; ++reg)
        skb[(size_t)(cB + reg) * TB + t0 + t] = accS[r][j][reg] + bsk[r][reg];
      if (last) {
#pragma unroll
        for (int reg = 0; reg < 4; ++reg)
          fxb[(size_t)(cB + reg) * TB + t0 + t] = vout[reg];
      } else {
        u32 ho[4], lo4[4];
#pragma unroll
        for (int reg = 0; reg < 4; ++reg) {
          unsigned short h = f2b(vout[reg]);
          ho[reg] = h;
          lo4[reg] = f2b(vout[reg] - b2fu(h));
        }
        uint2 hq, lq;
        hq.x = ho[0] | (ho[1] << 16); hq.y = ho[2] | (ho[3] << 16);
        lq.x = lo4[0] | (lo4[1] << 16); lq.y = lo4[2] | (lo4[3] << 16);
        *reinterpret_cast<uint2*>(reinterpret_cast<char*>(&Xs[0][0]) + swz(t, cB * 2)) = hq;
        *reinterpret_cast<uint2*>(reinterpret_cast<char*>(&Xs[1][0]) + swz(t, cB * 2)) = lq;
      }
    }
  }

  if (!last) {
    __syncthreads();
    unsigned short* hrow = hout + ((size_t)b * TB + t0) * CC;
    unsigned short* lwrow = lob + ((size_t)b * TB + t0) * CC;
#pragma unroll
    for (int it = 0; it < 4; ++it) {
      int o = it * 4096 + tid * 16;
      int t = o >> 8;
      int cb = (o & 255) ^ ((t & 7) << 4);
      *reinterpret_cast<f32x4*>(reinterpret_cast<char*>(hrow) + (size_t)t * 256 + cb) =
          *reinterpret_cast<f32x4*>(reinterpret_cast<char*>(&Xs[0][0]) + o);
      *reinterpret_cast<f32x4*>(reinterpret_cast<char*>(lwrow) + (size_t)t * 256 + cb) =
          *reinterpret_cast<f32x4*>(reinterpret_cast<char*>(&Xs[1][0]) + o);
    }
  }
}

extern "C" void kernel_launch(void* const* d_in, const int* in_sizes, int n_in,
                              void* d_out, int out_size, void* d_ws, size_t ws_size,
                              hipStream_t stream) {
  const float* x0    = (const float*)d_in[0];
  const float* Wconv = (const float*)d_in[1];
  const float* bconv = (const float*)d_in[2];
  const float* Wout  = (const float*)d_in[3];
  const float* bout  = (const float*)d_in[4];
  const float* Wskip = (const float*)d_in[5];
  const float* bskip = (const float*)d_in[6];

  unsigned short* wc  = (unsigned short*)d_ws;   // [L][3][256][128] bf16
  unsigned short* wo  = wc + NCONV;              // [L][128][128] bf16
  unsigned short* wsk = wo + NMAT;               // [L][128][128] bf16
  unsigned short* zp  = wsk + NMAT;              // 256B zero page
  unsigned short* hiA = zp + 128;                // [B][T][C] bf16 hi plane A
  unsigned short* lob = hiA + XN;                // [B][T][C] bf16 lo plane
  // ws total = 38.8 MB

  float* fx = (float*)d_out;                      // final x region [B][C][T]
  float* skips = fx + XN;                         // [L][B][S][T]
  unsigned short* hiB = (unsigned short*)d_out;   // hi plane B aliased in x region
  // parity: x0t->hiB; even layers read hiB write hiA; odd read hiA write hiB.
  // l19 (odd) reads hiA and writes f32 over hiB's region -> no race.

  prep_kernel<<<(NCONV + 255) / 256, 256, 0, stream>>>(Wconv, Wout, Wskip, wc, wo, wsk, zp);
  x0t_kernel<<<dim3(TB / TT, BB), 256, 0, stream>>>(x0, hiB, lob);

  for (int l = 0; l < L_NUM; ++l) {
    const unsigned short* hin = (l % 2 == 0) ? hiB : hiA;
    unsigned short* hout      = (l % 2 == 0) ? hiA : hiB;
    layer_kernel<<<dim3(TB / TT, BB), 256, 0, stream>>>(
        hin, hout, lob, zp,
        wc + (size_t)l * 3 * 256 * 128, bconv + (size_t)l * 256,
        wo + (size_t)l * 128 * 128, bout + (size_t)l * 128,
        wsk + (size_t)l * 128 * 128, bskip + (size_t)l * 128,
        skips + (size_t)l * XN, fx,
        DILS[l], l == L_NUM - 1 ? 1 : 0);
  }
}